// Round 2
// baseline (460.959 us; speedup 1.0000x reference)
//
#include <hip/hip_runtime.h>
#include <cstdint>

#define B_ 64
#define M_ 1024
#define F_ 4
#define E_ 256
#define NW_ 32000
#define PL_ 128

// output element offsets (fp32 elements)
#define P_OFF   0
#define PV_OFF  65536
#define PR_OFF  2113536
#define H_OFF   2179072

typedef unsigned short u16;
typedef unsigned int u32;

typedef __bf16 bf16x8 __attribute__((ext_vector_type(8)));
typedef float f32x4 __attribute__((ext_vector_type(4)));

__device__ __forceinline__ u16 f2bf(float f) {
    u32 x = __builtin_bit_cast(u32, f);
    u32 r = (x + 0x7fffu + ((x >> 16) & 1u)) >> 16;
    return (u16)r;
}
__device__ __forceinline__ float bf2f(u16 h) {
    return __builtin_bit_cast(float, (u32)h << 16);
}
__device__ __forceinline__ uint4 pack8(const float* s) {
    uint4 u;
    u.x = (u32)f2bf(s[0]) | ((u32)f2bf(s[1]) << 16);
    u.y = (u32)f2bf(s[2]) | ((u32)f2bf(s[3]) << 16);
    u.z = (u32)f2bf(s[4]) | ((u32)f2bf(s[5]) << 16);
    u.w = (u32)f2bf(s[6]) | ((u32)f2bf(s[7]) << 16);
    return u;
}
__device__ __forceinline__ bf16x8 pack_bf8(float4 a, float4 b) {
    union { u16 s[8]; bf16x8 v; } u;
    u.s[0] = f2bf(a.x); u.s[1] = f2bf(a.y); u.s[2] = f2bf(a.z); u.s[3] = f2bf(a.w);
    u.s[4] = f2bf(b.x); u.s[5] = f2bf(b.y); u.s[6] = f2bf(b.z); u.s[7] = f2bf(b.w);
    return u.v;
}

// ---------------------------------------------------------------------------
// K1: GRU step + profile encoding.  Also inits q1=q2=h and builds Qcat0
// (bf16 hi/lo rows of q0) for the S0 GEMM.  64 blocks x 256 threads.
// ---------------------------------------------------------------------------
__global__ __launch_bounds__(256) void k_gru(
    const float* __restrict__ tables, const float* __restrict__ Wih,
    const float* __restrict__ Whh, const float* __restrict__ bih,
    const float* __restrict__ bhh, const float* __restrict__ Wp,
    const float* __restrict__ bp, const int* __restrict__ y,
    const float* __restrict__ h_, const float* __restrict__ pe,
    float* __restrict__ q0, float* __restrict__ q1, float* __restrict__ q2,
    float* __restrict__ enc, float* __restrict__ outh, u16* __restrict__ Qc0)
{
    int b = blockIdx.x, t = threadIdx.x;
    __shared__ float m_s[E_], h_s[E_], pe_s[PL_];
    int yb = y[b];
    m_s[t] = tables[(size_t)NW_ * E_ + (size_t)yb * E_ + t];  // row 0 is zero
    h_s[t] = h_[b * E_ + t];
    if (t < PL_) pe_s[t] = pe[b * PL_ + t];
    __syncthreads();

    float g_i[3], g_h[3];
#pragma unroll
    for (int g = 0; g < 3; g++) {
        int j = g * E_ + t;
        float ai = bih[j], ah = bhh[j];
        const float4* wi = (const float4*)(Wih + (size_t)j * E_);
        const float4* wh = (const float4*)(Whh + (size_t)j * E_);
#pragma unroll 8
        for (int e = 0; e < E_ / 4; e++) {
            float4 a = wi[e], c = wh[e];
            ai += a.x * m_s[4 * e] + a.y * m_s[4 * e + 1] +
                  a.z * m_s[4 * e + 2] + a.w * m_s[4 * e + 3];
            ah += c.x * h_s[4 * e] + c.y * h_s[4 * e + 1] +
                  c.z * h_s[4 * e + 2] + c.w * h_s[4 * e + 3];
        }
        g_i[g] = ai; g_h[g] = ah;
    }
    float r = 1.f / (1.f + expf(-(g_i[0] + g_h[0])));
    float z = 1.f / (1.f + expf(-(g_i[1] + g_h[1])));
    float n = tanhf(g_i[2] + r * g_h[2]);
    float hv = (1.f - z) * n + z * h_s[t];
    q0[b * E_ + t] = hv;
    q1[b * E_ + t] = hv;     // q1 = h + o0 (o0 added by k_oacc)
    q2[b * E_ + t] = hv;     // q2 = h + o0 + o1
    outh[b * E_ + t] = hv;
    u16 hi = f2bf(hv);
    Qc0[(size_t)b * E_ + t] = hi;
    Qc0[(size_t)(B_ + b) * E_ + t] = f2bf(hv - bf2f(hi));

    float ea = bp[t];
    const float4* wp = (const float4*)(Wp + (size_t)t * PL_);
#pragma unroll 8
    for (int p = 0; p < PL_ / 4; p++) {
        float4 a = wp[p];
        ea += a.x * pe_s[4 * p] + a.y * pe_s[4 * p + 1] +
              a.z * pe_s[4 * p + 2] + a.w * pe_s[4 * p + 3];
    }
    enc[b * E_ + t] = ea;
}

// ---------------------------------------------------------------------------
// K_qprep: build Qcat (bf16 hi/lo rows of q [+ q*enc]) for S-GEMMs.
// 64 blocks x 256.  WE=1 adds rows 128..255 = hi/lo of q*enc.
// ---------------------------------------------------------------------------
template <int WE>
__global__ __launch_bounds__(256) void k_qprep(
    const float* __restrict__ qsrc, const float* __restrict__ enc,
    u16* __restrict__ Qc)
{
    int b = blockIdx.x, t = threadIdx.x;
    float v = qsrc[b * E_ + t];
    u16 hi = f2bf(v);
    Qc[(size_t)b * E_ + t] = hi;
    Qc[(size_t)(B_ + b) * E_ + t] = f2bf(v - bf2f(hi));
    if (WE) {
        float e = v * enc[b * E_ + t];
        u16 h2 = f2bf(e);
        Qc[(size_t)(2 * B_ + b) * E_ + t] = h2;
        Qc[(size_t)(3 * B_ + b) * E_ + t] = f2bf(e - bf2f(h2));
    }
}

// ---------------------------------------------------------------------------
// K_sgemm: S[b][w] = <T[w], q[b]> via MFMA 16x16x32 bf16 with q hi/lo split.
// A = table rows (fp32 -> bf16 in-register), B = Qcat rows (bf16).
// Both operands are K(e)-contiguous: no LDS staging for the K-loop.
// NQ = number of 64-row q groups (2: hi/lo -> one output; 4: -> two outputs).
// grid 500 blocks (64 w-rows each) x 256 threads (4 waves, wave = 16 w-rows).
// Epilogue combines hi+lo tiles and transposes through LDS for coalesced
// [b][w] stores.
// ---------------------------------------------------------------------------
template <int NQ>
__global__ __launch_bounds__(256) void k_sgemm(
    const float* __restrict__ T, const u16* __restrict__ Qc,
    float* __restrict__ OA, float* __restrict__ OB)
{
    constexpr int NT = NQ * 4;
    __shared__ float lds[64][65];
    int t = threadIdx.x, lane = t & 63, wv = t >> 6;
    int l15 = lane & 15, quad = lane >> 4;
    int w0 = blockIdx.x * 64;
    const float* arow = T + (size_t)(w0 + wv * 16 + l15) * E_;
    f32x4 acc[NT];
#pragma unroll
    for (int nt = 0; nt < NT; nt++) acc[nt] = f32x4{0.f, 0.f, 0.f, 0.f};
#pragma unroll
    for (int ks = 0; ks < 8; ks++) {
        int k0 = ks * 32 + quad * 8;
        float4 a0 = *(const float4*)(arow + k0);
        float4 a1 = *(const float4*)(arow + k0 + 4);
        bf16x8 af = pack_bf8(a0, a1);
#pragma unroll
        for (int nt = 0; nt < NT; nt++) {
            bf16x8 bfr = *(const bf16x8*)(Qc + (size_t)(nt * 16 + l15) * E_ + k0);
            acc[nt] = __builtin_amdgcn_mfma_f32_16x16x32_bf16(af, bfr, acc[nt], 0, 0, 0);
        }
    }
#pragma unroll
    for (int arr = 0; arr < NQ / 2; arr++) {
        float* O = arr ? OB : OA;
        if (arr) __syncthreads();
#pragma unroll
        for (int nt = 0; nt < 4; nt++)
#pragma unroll
            for (int j = 0; j < 4; j++)
                lds[wv * 16 + quad * 4 + j][nt * 16 + l15] =
                    acc[arr * 8 + nt][j] + acc[arr * 8 + nt + 4][j];
        __syncthreads();
        int bb = t >> 2, ws = (t & 3) * 16;
        float vv[16];
#pragma unroll
        for (int i = 0; i < 16; i++) vv[i] = lds[ws + i][bb];
        float* orow = O + (size_t)bb * NW_ + w0 + ws;
        *(float4*)(orow)      = make_float4(vv[0], vv[1], vv[2], vv[3]);
        *(float4*)(orow + 4)  = make_float4(vv[4], vv[5], vv[6], vv[7]);
        *(float4*)(orow + 8)  = make_float4(vv[8], vv[9], vv[10], vv[11]);
        *(float4*)(orow + 12) = make_float4(vv[12], vv[13], vv[14], vv[15]);
    }
}

// ---------------------------------------------------------------------------
// K_gsm: p[b,m] = sum_f S[b][ctx[b,m,f]]  (4B gathers from L2-resident slice)
// + softmax over m -> attn.  MODE 1: also p_resto from SR -> out[PR].
// 64 blocks (one per b) x 256 threads, thread handles 4 m.
// ---------------------------------------------------------------------------
template <int MODE>
__global__ __launch_bounds__(256) void k_gsm(
    const float* __restrict__ S, const float* __restrict__ SR,
    const int* __restrict__ ctx, float* __restrict__ attn,
    float* __restrict__ outpr)
{
    int b = blockIdx.x, t = threadIdx.x;
    const float* Sb = S + (size_t)b * NW_;
    const int4* cp = (const int4*)(ctx + ((size_t)b * M_ + t * 4) * F_);
    int4 c0 = cp[0], c1 = cp[1], c2 = cp[2], c3 = cp[3];
    float p0 = Sb[c0.x] + Sb[c0.y] + Sb[c0.z] + Sb[c0.w];
    float p1 = Sb[c1.x] + Sb[c1.y] + Sb[c1.z] + Sb[c1.w];
    float p2 = Sb[c2.x] + Sb[c2.y] + Sb[c2.z] + Sb[c2.w];
    float p3 = Sb[c3.x] + Sb[c3.y] + Sb[c3.z] + Sb[c3.w];
    if constexpr (MODE == 1) {
        const float* Rb = SR + (size_t)b * NW_;
        float r0 = Rb[c0.x] + Rb[c0.y] + Rb[c0.z] + Rb[c0.w];
        float r1 = Rb[c1.x] + Rb[c1.y] + Rb[c1.z] + Rb[c1.w];
        float r2 = Rb[c2.x] + Rb[c2.y] + Rb[c2.z] + Rb[c2.w];
        float r3 = Rb[c3.x] + Rb[c3.y] + Rb[c3.z] + Rb[c3.w];
        *(float4*)(outpr + PR_OFF + (size_t)b * M_ + t * 4) =
            make_float4(r0, r1, r2, r3);
    }
    __shared__ float red[256];
    float lm = fmaxf(fmaxf(p0, p1), fmaxf(p2, p3));
    red[t] = lm;
    __syncthreads();
    for (int s = 128; s > 0; s >>= 1) {
        if (t < s) red[t] = fmaxf(red[t], red[t + s]);
        __syncthreads();
    }
    float mx = red[0];
    __syncthreads();
    float e0 = expf(p0 - mx), e1 = expf(p1 - mx);
    float e2 = expf(p2 - mx), e3 = expf(p3 - mx);
    red[t] = e0 + e1 + e2 + e3;
    __syncthreads();
    for (int s = 128; s > 0; s >>= 1) {
        if (t < s) red[t] += red[t + s];
        __syncthreads();
    }
    float inv = 1.f / red[0];
    *(float4*)(attn + (size_t)b * M_ + t * 4) =
        make_float4(e0 * inv, e1 * inv, e2 * inv, e3 * inv);
}

// ---------------------------------------------------------------------------
// K_g2: final hop scores p[b,m] = sum_f S2[b][ctx[b,m,f]] -> out (no softmax).
// grid (4,64) x 256, thread per m.
// ---------------------------------------------------------------------------
__global__ __launch_bounds__(256) void k_g2(
    const float* __restrict__ S, const int* __restrict__ ctx,
    float* __restrict__ out)
{
    int b = blockIdx.y;
    int m = blockIdx.x * 256 + threadIdx.x;
    const float* Sb = S + (size_t)b * NW_;
    int4 c = *(const int4*)(ctx + ((size_t)b * M_ + m) * F_);
    out[P_OFF + (size_t)b * M_ + m] = Sb[c.x] + Sb[c.y] + Sb[c.z] + Sb[c.w];
}

// ---------------------------------------------------------------------------
// K_oacc: o[b] += sum_m attn[m] * sum_f T[ctx[b,m,f]]  (fp32 table gather,
// full precision -- better than old bf16 mems path).  grid (8,64) x 256:
// block handles 128 m (512 rows); thread t owns column e=t; row address is
// wave-uniform (LDS broadcast), loads are 1KB-coalesced per block.
// Result atomically added into q1 (and q2 when NADD=2).
// ---------------------------------------------------------------------------
template <int NADD>
__global__ __launch_bounds__(256) void k_oacc(
    const float* __restrict__ T, const int* __restrict__ ctx,
    const float* __restrict__ attn, float* __restrict__ qa,
    float* __restrict__ qb)
{
    int b = blockIdx.y, chv = blockIdx.x, t = threadIdx.x;
    int m0 = chv * 128;
    __shared__ int cidx[512];
    __shared__ float aw[128];
    if (t < 128) aw[t] = attn[(size_t)b * M_ + m0 + t];
    ((int2*)cidx)[t] = ((const int2*)(ctx + ((size_t)b * M_ + m0) * F_))[t];
    __syncthreads();
    float acc0 = 0.f, acc1 = 0.f;
#pragma unroll 8
    for (int r = 0; r < 512; r += 2) {
        acc0 += aw[r >> 2]       * T[(size_t)cidx[r] * E_ + t];
        acc1 += aw[(r + 1) >> 2] * T[(size_t)cidx[r + 1] * E_ + t];
    }
    float acc = acc0 + acc1;
    atomicAdd(qa + b * E_ + t, acc);
    if constexpr (NADD == 2) atomicAdd(qb + b * E_ + t, acc);
}

// ---------------------------------------------------------------------------
// K7: p_vocab = [h ; o0] @ Wv^T + bv via MFMA 16x16x32 bf16.  (unchanged)
// ---------------------------------------------------------------------------
__global__ __launch_bounds__(256) void k_pvocab(
    const float* __restrict__ Wv, const float* __restrict__ bv,
    const float* __restrict__ q0, const float* __restrict__ q1,
    float* __restrict__ out)
{
    __shared__ u16 X[64 * 512];  // 64KB
    int t = threadIdx.x;
#pragma unroll
    for (int it = 0; it < 16; it++) {
        int id = t + it * 256;
        int bb = id >> 6, c = id & 63;
        float v[8];
        if (c < 32) {
            const float* s = q0 + bb * E_ + c * 8;
#pragma unroll
            for (int j = 0; j < 8; j++) v[j] = s[j];
        } else {
            const float* s1 = q1 + bb * E_ + (c - 32) * 8;
            const float* s0 = q0 + bb * E_ + (c - 32) * 8;
#pragma unroll
            for (int j = 0; j < 8; j++) v[j] = s1[j] - s0[j];
        }
        uint4 uv = pack8(v);
        *(uint4*)(&X[bb * 512 + ((c ^ (bb & 7)) << 3)]) = uv;
    }
    __syncthreads();

    int lane = t & 63, w = t >> 6;
    int n0 = blockIdx.x * 128 + w * 32;
    int l15 = lane & 15, quad = lane >> 4;
    f32x4 acc[4][2];
#pragma unroll
    for (int mt = 0; mt < 4; mt++)
#pragma unroll
        for (int nt = 0; nt < 2; nt++)
            acc[mt][nt] = f32x4{0.f, 0.f, 0.f, 0.f};

    for (int ks = 0; ks < 16; ks++) {
        bf16x8 a[4], bfr[2];
#pragma unroll
        for (int mt = 0; mt < 4; mt++) {
            int m = mt * 16 + l15;
            int c = ks * 4 + quad;
            a[mt] = *(const bf16x8*)(&X[m * 512 + ((c ^ (m & 7)) << 3)]);
        }
#pragma unroll
        for (int nt = 0; nt < 2; nt++) {
            int n = n0 + nt * 16 + l15;
            const float4* wp = (const float4*)(Wv + (size_t)n * 512 + ks * 32 + quad * 8);
            bfr[nt] = pack_bf8(wp[0], wp[1]);
        }
#pragma unroll
        for (int mt = 0; mt < 4; mt++)
#pragma unroll
            for (int nt = 0; nt < 2; nt++)
                acc[mt][nt] = __builtin_amdgcn_mfma_f32_16x16x32_bf16(
                    a[mt], bfr[nt], acc[mt][nt], 0, 0, 0);
    }
#pragma unroll
    for (int nt = 0; nt < 2; nt++) {
        int n = n0 + nt * 16 + l15;
        float bvv = bv[n];
#pragma unroll
        for (int mt = 0; mt < 4; mt++) {
#pragma unroll
            for (int j = 0; j < 4; j++) {
                int m = mt * 16 + quad * 4 + j;
                out[PV_OFF + (size_t)m * 32000 + n] = acc[mt][nt][j] + bvv;
            }
        }
    }
}

// ---------------------------------------------------------------------------
extern "C" void kernel_launch(void* const* d_in, const int* in_sizes, int n_in,
                              void* d_out, int out_size, void* d_ws, size_t ws_size,
                              hipStream_t stream)
{
    const float* tables = (const float*)d_in[0];
    const float* Wih = (const float*)d_in[1];
    const float* Whh = (const float*)d_in[2];
    const float* bih = (const float*)d_in[3];
    const float* bhh = (const float*)d_in[4];
    const float* Wp  = (const float*)d_in[5];
    const float* bp  = (const float*)d_in[6];
    const float* Wv  = (const float*)d_in[7];
    const float* bv  = (const float*)d_in[8];
    const int* ctx = (const int*)d_in[9];
    const int* y   = (const int*)d_in[10];
    const float* h_  = (const float*)d_in[11];
    const float* pe  = (const float*)d_in[12];
    float* out = (float*)d_out;

    // ws layout (total ~33.6 MB)
    float* Wf   = (float*)d_ws;
    float* q0v  = Wf;                       // 16384 f
    float* q1v  = Wf + 16384;
    float* q2v  = Wf + 32768;
    float* encv = Wf + 49152;
    float* attn = Wf + 65536;               // 65536 f
    u16* Qc0 = (u16*)(Wf + 131072);         // 128x256 u16
    u16* Qc1 = Qc0 + 32768;                 // 256x256 u16
    u16* Qc2 = Qc1 + 65536;                 // 128x256 u16
    float* S0 = (float*)(Qc2 + 32768);      // 64x32000 f each
    float* S1 = S0 + (size_t)B_ * NW_;
    float* SRb = S1 + (size_t)B_ * NW_;
    float* S2 = SRb + (size_t)B_ * NW_;
    const float* T0 = tables;
    const float* T1 = tables + (size_t)NW_ * E_;
    const float* T2 = tables + 2 * (size_t)NW_ * E_;

    k_gru<<<64, 256, 0, stream>>>(tables, Wih, Whh, bih, bhh, Wp, bp, y, h_, pe,
                                  q0v, q1v, q2v, encv, out + H_OFF, Qc0);
    // hop 0: word-space scores S0 = T0 . q0(hi/lo), gather+softmax, o0
    k_sgemm<2><<<500, 256, 0, stream>>>(T0, Qc0, S0, nullptr);
    k_gsm<0><<<64, 256, 0, stream>>>(S0, nullptr, ctx, attn, nullptr);
    k_oacc<2><<<dim3(8, 64), 256, 0, stream>>>(T1, ctx, attn, q1v, q2v);
    // hop 1: S1 = T1 . q1(hi/lo), SR = T1 . (q1*enc)(hi/lo)
    k_qprep<1><<<64, 256, 0, stream>>>(q1v, encv, Qc1);
    k_sgemm<4><<<500, 256, 0, stream>>>(T1, Qc1, S1, SRb);
    k_gsm<1><<<64, 256, 0, stream>>>(S1, SRb, ctx, attn, out);
    k_oacc<1><<<dim3(8, 64), 256, 0, stream>>>(T2, ctx, attn, q2v, nullptr);
    // hop 2: S2 = T2 . q2(hi/lo), final p -> out
    k_qprep<0><<<64, 256, 0, stream>>>(q2v, nullptr, Qc2);
    k_sgemm<2><<<500, 256, 0, stream>>>(T2, Qc2, S2, nullptr);
    k_g2<<<dim3(4, 64), 256, 0, stream>>>(S2, ctx, out);
    // p_vocab head (needs q0, q1)
    k_pvocab<<<250, 256, 0, stream>>>(Wv, bv, q0v, q1v, out);
}